// Round 3
// baseline (1499.170 us; speedup 1.0000x reference)
//
#include <hip/hip_runtime.h>

#define T_STEPS 100
#define B_SZ    2048
#define IN_DIM  784
#define HID_DIM 100
#define OUT_DIM 10
#define BM      128
#define KC      8
#define NSTEP   (IN_DIM / KC)   // 98

// ---------------- w1 -> double (once; L2-resident, read by all GEMM blocks) ----------------
__global__ void cvt_w1(const float* __restrict__ w1, double* __restrict__ wd) {
  int i = blockIdx.x * 256 + threadIdx.x;
  if (i < HID_DIM * IN_DIM) wd[i] = (double)w1[i];
}

// ---------------- Phase A: cur[r][h] = sum_k x[r][k]*w1[h][k], fp64 acc ----------------
// 256 thr: hg = tid>>6 (wave-uniform, 25 h's each), rows rg & rg+64 (mi=2), full k.
// w from GLOBAL via wave-uniform addresses (scalar/L1 path) — LDS only stages x.
__global__ __launch_bounds__(256, 2)
void snn_gemm1(const float* __restrict__ x,
               const double* __restrict__ wd,
               double* __restrict__ cur)
{
  const int tid = threadIdx.x;
  const int rg  = tid & 63;
  const int hg  = __builtin_amdgcn_readfirstlane(tid >> 6);  // 0..3, uniform per wave
  const int h0  = hg * 25;
  const long rowBase = (long)blockIdx.x * BM;

  __shared__ float xs[2][BM][KC + 1];   // pad 9 -> conflict-free scalar reads

  // staging: thread t loads one float4: row = t>>1, half = t&1
  const int srow = tid >> 1;
  const int spar = tid & 1;
  const float* xsrc = x + (rowBase + srow) * (long)IN_DIM + spar * 4;

  float4 g;
  auto LOADG = [&](int s) {
    g = *reinterpret_cast<const float4*>(xsrc + s * KC);
  };
  auto STORE = [&](int buf) {
    float* d = &xs[buf][srow][spar * 4];
    d[0] = g.x; d[1] = g.y; d[2] = g.z; d[3] = g.w;
  };

  double acc[2][25];
#pragma unroll
  for (int mi = 0; mi < 2; ++mi)
#pragma unroll
    for (int hi = 0; hi < 25; ++hi) acc[mi][hi] = 0.0;

  const double* wbase = wd + (long)h0 * IN_DIM;

  LOADG(0); STORE(0); LOADG(1);
  __syncthreads();

#pragma unroll 1
  for (int s = 0; s < NSTEP; ++s) {
    if (s + 1 < NSTEP) STORE((s + 1) & 1);
    if (s + 2 < NSTEP) LOADG(s + 2);
    const int buf = s & 1;

    double dx[2][KC];
#pragma unroll
    for (int j = 0; j < KC; ++j) {
      dx[0][j] = (double)xs[buf][rg][j];
      dx[1][j] = (double)xs[buf][rg + 64][j];
    }

    const double* wp = wbase + s * KC;
#pragma unroll
    for (int hi = 0; hi < 25; ++hi) {
      const double* wrow = wp + hi * IN_DIM;   // wave-uniform, 64B-aligned, 8 doubles
#pragma unroll
      for (int j = 0; j < KC; ++j) {
        const double wv = wrow[j];
        acc[0][hi] = fma(dx[0][j], wv, acc[0][hi]);
        acc[1][hi] = fma(dx[1][j], wv, acc[1][hi]);
      }
    }
    __syncthreads();
  }

#pragma unroll
  for (int mi = 0; mi < 2; ++mi) {
    double* cp = cur + (rowBase + mi * 64 + rg) * HID_DIM + h0;
#pragma unroll
    for (int hi = 0; hi < 25; ++hi) cp[hi] = acc[mi][hi];
  }
}

// ---------------- Phase B: serial-in-time recursion, fp64 state (unchanged, ~20us) ----------------
__global__ __launch_bounds__(256)
void snn_recur(const double* __restrict__ cur,  // [chunkT][2048][100]
               const float* __restrict__ w2,    // [10][100]
               double* __restrict__ mem1s, float* __restrict__ spk1s,
               double* __restrict__ mem2s, float* __restrict__ spk2s,
               float* __restrict__ outs,
               float* __restrict__ dout,
               int chunkT, int isFirst, int isLast)
{
  const int tid = threadIdx.x;
  const int b0  = blockIdx.x * 8;
  __shared__ float w2l[OUT_DIM * HID_DIM];
  __shared__ float spkl[8 * HID_DIM];

  if (tid < 250)
    reinterpret_cast<float4*>(w2l)[tid] = reinterpret_cast<const float4*>(w2)[tid];

  const bool pa = tid < 200;
  const long aOff = (long)b0 * HID_DIM + tid * 4;
  double m1[4] = {0.0, 0.0, 0.0, 0.0};
  float4 s1 = make_float4(0.f, 0.f, 0.f, 0.f);
  if (pa && !isFirst) {
    const double2* mp = reinterpret_cast<const double2*>(mem1s + aOff);
    double2 a = mp[0], b = mp[1];
    m1[0] = a.x; m1[1] = a.y; m1[2] = b.x; m1[3] = b.y;
    s1 = *reinterpret_cast<const float4*>(spk1s + aOff);
  }

  const bool pb = tid < 80;
  const int  ss = tid / 10, oo = tid % 10;
  const long bOff = (long)b0 * OUT_DIM + tid;
  double m2 = 0.0;
  float s2 = 0.f, oacc = 0.f;
  if (pb && !isFirst) { m2 = mem2s[bOff]; s2 = spk2s[bOff]; oacc = outs[bOff]; }

  __syncthreads();

  for (int tt = 0; tt < chunkT; ++tt) {
    if (pa) {
      const double2* cp = reinterpret_cast<const double2*>(
          cur + ((long)tt * B_SZ + b0) * HID_DIM + tid * 4);
      const double2 ca = cp[0], cb = cp[1];
      double cu[4] = {ca.x, ca.y, cb.x, cb.y};
      float4 sp;
      float* spv = &sp.x;
      const float* s1v = &s1.x;
#pragma unroll
      for (int j = 0; j < 4; ++j) {
        double m = 0.9 * m1[j];
        m = m + cu[j];
        m = m - (double)s1v[j];
        spv[j] = (m > 1.0) ? 1.0f : 0.0f;
        m1[j] = m;
      }
      s1 = sp;
      *reinterpret_cast<float4*>(&spkl[tid * 4]) = sp;
    }
    __syncthreads();
    if (pb) {
      const float* sr = &spkl[ss * HID_DIM];
      const float* wr = &w2l[oo * HID_DIM];
      double a0 = 0.0, a1 = 0.0, a2 = 0.0, a3 = 0.0;
#pragma unroll
      for (int h = 0; h < 100; h += 4) {
        a0 = fma((double)sr[h],     (double)wr[h],     a0);
        a1 = fma((double)sr[h + 1], (double)wr[h + 1], a1);
        a2 = fma((double)sr[h + 2], (double)wr[h + 2], a2);
        a3 = fma((double)sr[h + 3], (double)wr[h + 3], a3);
      }
      const double a = (a0 + a1) + (a2 + a3);
      double m = 0.9 * m2;
      m = m + a;
      m = m - (double)s2;
      const float sp = (m > 1.0) ? 1.0f : 0.0f;
      m2 = m; s2 = sp; oacc += sp;
    }
    __syncthreads();
  }

  if (pa) {
    double2* mp = reinterpret_cast<double2*>(mem1s + aOff);
    mp[0] = make_double2(m1[0], m1[1]);
    mp[1] = make_double2(m1[2], m1[3]);
    *reinterpret_cast<float4*>(spk1s + aOff) = s1;
  }
  if (pb) {
    mem2s[bOff] = m2; spk2s[bOff] = s2; outs[bOff] = oacc;
    if (isLast) dout[bOff] = oacc;
  }
}

// ---------------- host ----------------
extern "C" void kernel_launch(void* const* d_in, const int* in_sizes, int n_in,
                              void* d_out, int out_size, void* d_ws, size_t ws_size,
                              hipStream_t stream) {
  const float* x  = (const float*)d_in[0];   // [100,2048,784]
  const float* w1 = (const float*)d_in[1];   // [100,784]
  const float* w2 = (const float*)d_in[2];   // [10,100]
  float* out = (float*)d_out;

  char* ws = (char*)d_ws;
  // bytes: wd(d) 627,200 | mem1(d) 1,638,400 | spk1(f) 819,200 | mem2(d) 163,840 |
  //        spk2(f) 81,920 | outacc(f) 81,920 | cur(d)...
  double* wd    = (double*)(ws);
  double* mem1s = (double*)(ws + 627200);
  float*  spk1s = (float*) (ws + 2265600);
  double* mem2s = (double*)(ws + 3084800);
  float*  spk2s = (float*) (ws + 3248640);
  float*  outs  = (float*) (ws + 3330560);
  double* cur   = (double*)(ws + 3412480);

  cvt_w1<<<dim3((HID_DIM * IN_DIM + 255) / 256), dim3(256), 0, stream>>>(w1, wd);

  const size_t perT = (size_t)B_SZ * HID_DIM * 8;  // 1,638,400 B of cur per timestep
  size_t curCap = ws_size > (size_t)3412480 ? ws_size - 3412480 : 0;
  int Tc = (int)(curCap / perT);
  if (Tc > T_STEPS) Tc = T_STEPS;
  if (Tc < 1) Tc = 1;

  for (int t0 = 0; t0 < T_STEPS; t0 += Tc) {
    const int ct = (T_STEPS - t0 < Tc) ? (T_STEPS - t0) : Tc;
    snn_gemm1<<<dim3(ct * (B_SZ / BM)), dim3(256), 0, stream>>>(
        x + (size_t)t0 * B_SZ * IN_DIM, wd, cur);
    snn_recur<<<dim3(B_SZ / 8), dim3(256), 0, stream>>>(
        cur, w2, mem1s, spk1s, mem2s, spk2s, outs, out,
        ct, (t0 == 0) ? 1 : 0, (t0 + ct >= T_STEPS) ? 1 : 0);
  }
}

// Round 4
// 1457.135 us; speedup vs baseline: 1.0288x; 1.0288x over previous
//
#include <hip/hip_runtime.h>

#define T_STEPS 100
#define B_SZ    2048
#define IN_DIM  784
#define HID_DIM 100
#define OUT_DIM 10
#define BM      64
#define KC      16
#define NSTEP   (IN_DIM / KC)   // 49
#define WROWS   104             // padded w rows per staged chunk (13 x 1KB slots)

// ---------------- w1 -> double once (pad rows 100..103 with zeros) ----------------
__global__ void cvt_w1(const float* __restrict__ w1, double* __restrict__ wd) {
  int i = blockIdx.x * 256 + threadIdx.x;
  if (i < WROWS * IN_DIM) wd[i] = (i < HID_DIM * IN_DIM) ? (double)w1[i] : 0.0;
}

// ---------------- Phase A: cur[r][h] = sum_k x[r][k]*w1[h][k], fp64 acc ----------------
// 256 thr, BM=64: thread = (row ln, wave-uniform h-group of 25). acc[25] = 50 VGPR.
// w double-buffered in LDS (broadcast b128 reads); x transposed [k][row] (conflict-free).
__global__ __launch_bounds__(256, 4)
void snn_gemm1(const float* __restrict__ x,
               const double* __restrict__ wd,
               double* __restrict__ cur)
{
  const int tid = threadIdx.x;
  const int ln  = tid & 63;
  const int wv  = __builtin_amdgcn_readfirstlane(tid >> 6);  // 0..3 wave-uniform
  const int h0  = wv * 25;
  const long rowBase = (long)blockIdx.x * BM;

  __shared__ double wsh[2][WROWS][KC];   // 2*104*16*8 = 26624 B
  __shared__ float  xsh[2][KC][BM];      // 2*16*64*4  =  8192 B

  // ---- w staging map: 13 slots x 1024B; slot g = wv + 4*i; lane covers 16B ----
  const int nw = (wv == 0) ? 4 : 3;
  int wo0[4];                    // byte offset within w buffer
  const double* wsrc[4];         // global source base (k-chunk 0)
#pragma unroll
  for (int i = 0; i < 4; ++i) {
    const int g = wv + 4 * i;
    const int o = (g << 10) + (ln << 4);
    wo0[i] = o;
    const int h  = o >> 7;         // o / 128
    const int jq = (o >> 4) & 7;   // double2 index within row
    wsrc[i] = wd + (long)h * IN_DIM + jq * 2;
  }

  // ---- x staging map: thread = (row tid>>2, quad tid&3), stored transposed ----
  const int xrow = tid >> 2;
  const int xq   = tid & 3;
  const float* xsrc = x + (rowBase + xrow) * (long)IN_DIM + xq * 4;

  double2 wreg[4];
  float4  xreg;

  auto WLOAD = [&](int s) {
#pragma unroll
    for (int i = 0; i < 4; ++i)
      if (i < nw)
        wreg[i] = *reinterpret_cast<const double2*>(wsrc[i] + s * KC);
  };
  auto WSTORE = [&](int buf) {
    char* base = reinterpret_cast<char*>(&wsh[buf][0][0]);
#pragma unroll
    for (int i = 0; i < 4; ++i)
      if (i < nw)
        *reinterpret_cast<double2*>(base + wo0[i]) = wreg[i];
  };
  auto XLOAD = [&](int s) {
    xreg = *reinterpret_cast<const float4*>(xsrc + s * KC);
  };
  auto XSTORE = [&](int buf) {
    xsh[buf][xq * 4 + 0][xrow] = xreg.x;
    xsh[buf][xq * 4 + 1][xrow] = xreg.y;
    xsh[buf][xq * 4 + 2][xrow] = xreg.z;
    xsh[buf][xq * 4 + 3][xrow] = xreg.w;
  };

  double acc[25];
#pragma unroll
  for (int hi = 0; hi < 25; ++hi) acc[hi] = 0.0;

  WLOAD(0); XLOAD(0);
  WSTORE(0); XSTORE(0);
  WLOAD(1); XLOAD(1);
  __syncthreads();

#pragma unroll 1
  for (int s = 0; s < NSTEP; ++s) {
    const int buf = s & 1, nbuf = buf ^ 1;
    if (s + 1 < NSTEP) { WSTORE(nbuf); XSTORE(nbuf); }
    if (s + 2 < NSTEP) { WLOAD(s + 2); XLOAD(s + 2); }

#pragma unroll
    for (int jp = 0; jp < KC / 2; ++jp) {
      const double xa = (double)xsh[buf][2 * jp][ln];
      const double xb = (double)xsh[buf][2 * jp + 1][ln];
#pragma unroll
      for (int hi = 0; hi < 25; ++hi) {
        const double2 w = *reinterpret_cast<const double2*>(&wsh[buf][h0 + hi][2 * jp]);
        acc[hi] = fma(xa, w.x, acc[hi]);
        acc[hi] = fma(xb, w.y, acc[hi]);
      }
    }
    __syncthreads();
  }

  double* cp = cur + (rowBase + ln) * HID_DIM + h0;
#pragma unroll
  for (int hi = 0; hi < 25; ++hi) cp[hi] = acc[hi];
}

// ---------------- Phase B: serial-in-time recursion, fp64 state (proven) ----------------
__global__ __launch_bounds__(256)
void snn_recur(const double* __restrict__ cur,  // [chunkT][2048][100]
               const float* __restrict__ w2,    // [10][100]
               double* __restrict__ mem1s, float* __restrict__ spk1s,
               double* __restrict__ mem2s, float* __restrict__ spk2s,
               float* __restrict__ outs,
               float* __restrict__ dout,
               int chunkT, int isFirst, int isLast)
{
  const int tid = threadIdx.x;
  const int b0  = blockIdx.x * 8;
  __shared__ float w2l[OUT_DIM * HID_DIM];
  __shared__ float spkl[8 * HID_DIM];

  if (tid < 250)
    reinterpret_cast<float4*>(w2l)[tid] = reinterpret_cast<const float4*>(w2)[tid];

  const bool pa = tid < 200;
  const long aOff = (long)b0 * HID_DIM + tid * 4;
  double m1[4] = {0.0, 0.0, 0.0, 0.0};
  float4 s1 = make_float4(0.f, 0.f, 0.f, 0.f);
  if (pa && !isFirst) {
    const double2* mp = reinterpret_cast<const double2*>(mem1s + aOff);
    double2 a = mp[0], b = mp[1];
    m1[0] = a.x; m1[1] = a.y; m1[2] = b.x; m1[3] = b.y;
    s1 = *reinterpret_cast<const float4*>(spk1s + aOff);
  }

  const bool pb = tid < 80;
  const int  ss = tid / 10, oo = tid % 10;
  const long bOff = (long)b0 * OUT_DIM + tid;
  double m2 = 0.0;
  float s2 = 0.f, oacc = 0.f;
  if (pb && !isFirst) { m2 = mem2s[bOff]; s2 = spk2s[bOff]; oacc = outs[bOff]; }

  __syncthreads();

  for (int tt = 0; tt < chunkT; ++tt) {
    if (pa) {
      const double2* cp = reinterpret_cast<const double2*>(
          cur + ((long)tt * B_SZ + b0) * HID_DIM + tid * 4);
      const double2 ca = cp[0], cb = cp[1];
      double cu[4] = {ca.x, ca.y, cb.x, cb.y};
      float4 sp;
      float* spv = &sp.x;
      const float* s1v = &s1.x;
#pragma unroll
      for (int j = 0; j < 4; ++j) {
        double m = 0.9 * m1[j];
        m = m + cu[j];
        m = m - (double)s1v[j];
        spv[j] = (m > 1.0) ? 1.0f : 0.0f;
        m1[j] = m;
      }
      s1 = sp;
      *reinterpret_cast<float4*>(&spkl[tid * 4]) = sp;
    }
    __syncthreads();
    if (pb) {
      const float* sr = &spkl[ss * HID_DIM];
      const float* wr = &w2l[oo * HID_DIM];
      double a0 = 0.0, a1 = 0.0, a2 = 0.0, a3 = 0.0;
#pragma unroll
      for (int h = 0; h < 100; h += 4) {
        a0 = fma((double)sr[h],     (double)wr[h],     a0);
        a1 = fma((double)sr[h + 1], (double)wr[h + 1], a1);
        a2 = fma((double)sr[h + 2], (double)wr[h + 2], a2);
        a3 = fma((double)sr[h + 3], (double)wr[h + 3], a3);
      }
      const double a = (a0 + a1) + (a2 + a3);
      double m = 0.9 * m2;
      m = m + a;
      m = m - (double)s2;
      const float sp = (m > 1.0) ? 1.0f : 0.0f;
      m2 = m; s2 = sp; oacc += sp;
    }
    __syncthreads();
  }

  if (pa) {
    double2* mp = reinterpret_cast<double2*>(mem1s + aOff);
    mp[0] = make_double2(m1[0], m1[1]);
    mp[1] = make_double2(m1[2], m1[3]);
    *reinterpret_cast<float4*>(spk1s + aOff) = s1;
  }
  if (pb) {
    mem2s[bOff] = m2; spk2s[bOff] = s2; outs[bOff] = oacc;
    if (isLast) dout[bOff] = oacc;
  }
}

// ---------------- host ----------------
extern "C" void kernel_launch(void* const* d_in, const int* in_sizes, int n_in,
                              void* d_out, int out_size, void* d_ws, size_t ws_size,
                              hipStream_t stream) {
  const float* x  = (const float*)d_in[0];   // [100,2048,784]
  const float* w1 = (const float*)d_in[1];   // [100,784]
  const float* w2 = (const float*)d_in[2];   // [10,100]
  float* out = (float*)d_out;

  char* ws = (char*)d_ws;
  // bytes: wd(d,padded 104 rows) 652,288 | mem1(d) 1,638,400 | spk1(f) 819,200 |
  //        mem2(d) 163,840 | spk2(f) 81,920 | outacc(f) 81,920 | cur(d)...
  double* wd    = (double*)(ws);
  double* mem1s = (double*)(ws +  652288);
  float*  spk1s = (float*) (ws + 2290688);
  double* mem2s = (double*)(ws + 3109888);
  float*  spk2s = (float*) (ws + 3273728);
  float*  outs  = (float*) (ws + 3355648);
  double* cur   = (double*)(ws + 3437568);

  cvt_w1<<<dim3((WROWS * IN_DIM + 255) / 256), dim3(256), 0, stream>>>(w1, wd);

  const size_t perT = (size_t)B_SZ * HID_DIM * 8;  // 1,638,400 B of cur per timestep
  size_t curCap = ws_size > (size_t)3437568 ? ws_size - 3437568 : 0;
  int Tc = (int)(curCap / perT);
  if (Tc > T_STEPS) Tc = T_STEPS;
  if (Tc < 1) Tc = 1;

  for (int t0 = 0; t0 < T_STEPS; t0 += Tc) {
    const int ct = (T_STEPS - t0 < Tc) ? (T_STEPS - t0) : Tc;
    snn_gemm1<<<dim3(ct * (B_SZ / BM)), dim3(256), 0, stream>>>(
        x + (size_t)t0 * B_SZ * IN_DIM, wd, cur);
    snn_recur<<<dim3(B_SZ / 8), dim3(256), 0, stream>>>(
        cur, w2, mem1s, spk1s, mem2s, spk2s, outs, out,
        ct, (t0 == 0) ? 1 : 0, (t0 + ct >= T_STEPS) ? 1 : 0);
  }
}

// Round 6
// 1226.231 us; speedup vs baseline: 1.2226x; 1.1883x over previous
//
#include <hip/hip_runtime.h>

#define T_STEPS 100
#define B_SZ    2048
#define IN_DIM  784
#define HID_DIM 100
#define OUT_DIM 10
#define BN      112           // padded hidden (7 x 16)
#define BMR     128           // rows per block
#define KC      16
#define NSTEP   (IN_DIM / KC) // 49
#define LDP     144           // LDS row stride (floats): 144%32==16 -> 2-way max (free)

typedef double f64x4 __attribute__((ext_vector_type(4)));
#define MFMA64(a, b, c) __builtin_amdgcn_mfma_f64_16x16x4f64((a), (b), (c), 0, 0, 0)

// ---------------- pad w1 to [112][784] float (rows 100..111 = 0) ----------------
__global__ void pad_w1(const float* __restrict__ w1, float* __restrict__ w1p) {
  int i = blockIdx.x * 256 + threadIdx.x;
  if (i < BN * IN_DIM) w1p[i] = (i < HID_DIM * IN_DIM) ? w1[i] : 0.0f;
}

// ---------------- Phase A: fp64 MFMA GEMM with self-calibrated fragment layout ----------------
__global__ __launch_bounds__(256)
void snn_gemm1(const float* __restrict__ x,     // [rows][784] (chunk-offset)
               const float* __restrict__ w1p,   // [112][784]
               double* __restrict__ cur)        // [rows][112]
{
  const int tid  = threadIdx.x;
  const int lane = tid & 63;
  const int wv   = tid >> 6;      // 0..3
  const int kg   = lane >> 4;     // 0..3 (assumed k-slot label)
  const int il   = lane & 15;     // assumed row/col label
  const long rowBase = (long)blockIdx.x * BMR;

  // ---- self-calibration probes: discover the true (lane,reg)->(row,col) D map ----
  f64x4 z = {0.0, 0.0, 0.0, 0.0};
  const double eil = (double)il;
  const double d0 = (kg == 0) ? 1.0 : 0.0;
  const double d1 = (kg == 1) ? 1.0 : 0.0;
  const double d2 = (kg == 2) ? 1.0 : 0.0;
  const double d3 = (kg == 3) ? 1.0 : 0.0;
  const f64x4 Prow0 = MFMA64(eil, d0, z);
  const f64x4 Prow1 = MFMA64(eil, d1, z);
  const f64x4 Pcol0 = MFMA64(d0, eil, z);
  const f64x4 Pcol1 = MFMA64(d1, eil, z);
  const f64x4 Pv0   = MFMA64(d0, d0, z);
  const f64x4 Pv1   = MFMA64(d1, d1, z);
  const f64x4 Pv2   = MFMA64(d2, d2, z);
  const f64x4 Pv3   = MFMA64(d3, d3, z);

  bool okl = true;
  int rowof[4], colof[4];
#pragma unroll
  for (int r = 0; r < 4; ++r) {
    okl = okl && (Pv0[r] == 1.0) && (Pv1[r] == 1.0) && (Pv2[r] == 1.0) && (Pv3[r] == 1.0);
    okl = okl && (Prow0[r] == Prow1[r]) && (Pcol0[r] == Pcol1[r]);
    const int rr = (int)Prow0[r];
    const int cc = (int)Pcol0[r];
    okl = okl && ((double)rr == Prow0[r]) && (rr >= 0) && (rr < 16);
    okl = okl && ((double)cc == Pcol0[r]) && (cc >= 0) && (cc < 16);
    rowof[r] = rr; colof[r] = cc;
  }
  const bool useMfma = (__all(okl ? 1 : 0) != 0);
  if (!useMfma) {
#pragma unroll
    for (int r = 0; r < 4; ++r) { rowof[r] = kg * 4 + r; colof[r] = il; }
  }

  __shared__ float xls[2][KC][LDP];   // 18432 B
  __shared__ float wls[2][KC][LDP];   // 18432 B

  // staging maps: thread t -> 8 floats of one row, k-half (t&1)*8
  const int  srow = tid >> 1;                  // x: 0..127 ; w: 0..111 (tid<224)
  const int  skh  = (tid & 1) * 8;
  const float* xsrc = x   + (rowBase + srow) * (long)IN_DIM + skh;
  const float* wsrc = w1p + (long)srow * IN_DIM + skh;
  const bool   dow  = tid < 2 * BN;            // 224 threads stage w

  float4 xa, xb, wa, wb;
  auto LOAD = [&](int s) {
    const float4* xp = reinterpret_cast<const float4*>(xsrc + s * KC);
    xa = xp[0]; xb = xp[1];
    if (dow) {
      const float4* wp = reinterpret_cast<const float4*>(wsrc + s * KC);
      wa = wp[0]; wb = wp[1];
    }
  };
  auto STORE = [&](int buf) {
    xls[buf][skh + 0][srow] = xa.x; xls[buf][skh + 1][srow] = xa.y;
    xls[buf][skh + 2][srow] = xa.z; xls[buf][skh + 3][srow] = xa.w;
    xls[buf][skh + 4][srow] = xb.x; xls[buf][skh + 5][srow] = xb.y;
    xls[buf][skh + 6][srow] = xb.z; xls[buf][skh + 7][srow] = xb.w;
    if (dow) {
      wls[buf][skh + 0][srow] = wa.x; wls[buf][skh + 1][srow] = wa.y;
      wls[buf][skh + 2][srow] = wa.z; wls[buf][skh + 3][srow] = wa.w;
      wls[buf][skh + 4][srow] = wb.x; wls[buf][skh + 5][srow] = wb.y;
      wls[buf][skh + 6][srow] = wb.z; wls[buf][skh + 7][srow] = wb.w;
    }
  };

  f64x4 acc[2][7];
#pragma unroll
  for (int rt = 0; rt < 2; ++rt)
#pragma unroll
    for (int ht = 0; ht < 7; ++ht) acc[rt][ht] = z;

  LOAD(0); STORE(0); LOAD(1);
  __syncthreads();

#pragma unroll 1
  for (int s = 0; s < NSTEP; ++s) {
    if (s + 1 < NSTEP) STORE((s + 1) & 1);
    if (s + 2 < NSTEP) LOAD(s + 2);
    const int buf = s & 1;

    if (useMfma) {
#pragma unroll
      for (int kk = 0; kk < 4; ++kk) {
        const int kr = kk * 4 + kg;
        const double a0 = (double)xls[buf][kr][wv * 32 + il];
        const double a1 = (double)xls[buf][kr][wv * 32 + 16 + il];
        double b[7];
#pragma unroll
        for (int ht = 0; ht < 7; ++ht)
          b[ht] = (double)wls[buf][kr][ht * 16 + il];
#pragma unroll
        for (int ht = 0; ht < 7; ++ht) {
          acc[0][ht] = MFMA64(a0, b[ht], acc[0][ht]);
          acc[1][ht] = MFMA64(a1, b[ht], acc[1][ht]);
        }
      }
    } else {
      // correct-but-slow VALU fallback over the same tiles (diagnostic path)
#pragma unroll 1
      for (int kr = 0; kr < KC; ++kr) {
        double wv7[7];
#pragma unroll
        for (int ht = 0; ht < 7; ++ht)
          wv7[ht] = (double)wls[buf][kr][ht * 16 + il];
#pragma unroll
        for (int rt = 0; rt < 2; ++rt)
#pragma unroll
          for (int m = 0; m < 4; ++m) {
            const double xv = (double)xls[buf][kr][wv * 32 + rt * 16 + kg * 4 + m];
#pragma unroll
            for (int ht = 0; ht < 7; ++ht)
              acc[rt][ht][m] = fma(xv, wv7[ht], acc[rt][ht][m]);
          }
      }
    }
    __syncthreads();
  }

  // epilogue through the calibrated D map
#pragma unroll
  for (int rt = 0; rt < 2; ++rt) {
    const long r0 = rowBase + wv * 32 + rt * 16;
#pragma unroll
    for (int ht = 0; ht < 7; ++ht)
#pragma unroll
      for (int m = 0; m < 4; ++m)
        cur[(r0 + rowof[m]) * BN + ht * 16 + colof[m]] = acc[rt][ht][m];
  }
}

// ---------------- Phase B: serial-in-time recursion, fp64 state (proven numerics) ----------------
__global__ __launch_bounds__(256)
void snn_recur(const double* __restrict__ cur,  // [chunkT][2048][112]
               const float* __restrict__ w2,    // [10][100]
               double* __restrict__ mem1s, float* __restrict__ spk1s,  // [2048][112]
               double* __restrict__ mem2s, float* __restrict__ spk2s,  // [2048][10]
               float* __restrict__ outs,
               float* __restrict__ dout,
               int chunkT, int isFirst, int isLast)
{
  const int tid = threadIdx.x;
  const int b0  = blockIdx.x * 8;
  __shared__ float w2l[OUT_DIM * HID_DIM];   // 1000
  __shared__ float spkl[8 * BN];             // 896

  if (tid < 250)
    reinterpret_cast<float4*>(w2l)[tid] = reinterpret_cast<const float4*>(w2)[tid];

  const bool pa = tid < 224;                 // 8 samples * 112 / 4
  const int  sl = tid / 28, q4 = (tid % 28) * 4;
  const long aOff = (long)(b0 + sl) * BN + q4;
  double m1[4] = {0.0, 0.0, 0.0, 0.0};
  float4 s1 = make_float4(0.f, 0.f, 0.f, 0.f);
  if (pa && !isFirst) {
    const double2* mp = reinterpret_cast<const double2*>(mem1s + aOff);
    double2 a = mp[0], b = mp[1];
    m1[0] = a.x; m1[1] = a.y; m1[2] = b.x; m1[3] = b.y;
    s1 = *reinterpret_cast<const float4*>(spk1s + aOff);
  }

  const bool pb = tid < 80;
  const int  ss = tid / 10, oo = tid % 10;
  const long bOff = (long)b0 * OUT_DIM + tid;
  double m2 = 0.0;
  float s2 = 0.f, oacc = 0.f;
  if (pb && !isFirst) { m2 = mem2s[bOff]; s2 = spk2s[bOff]; oacc = outs[bOff]; }

  __syncthreads();

  for (int tt = 0; tt < chunkT; ++tt) {
    if (pa) {
      const double2* cp = reinterpret_cast<const double2*>(
          cur + ((long)tt * B_SZ + b0 + sl) * BN + q4);
      const double2 ca = cp[0], cb = cp[1];
      double cu[4] = {ca.x, ca.y, cb.x, cb.y};
      float4 sp;
      float* spv = &sp.x;
      const float* s1v = &s1.x;
#pragma unroll
      for (int j = 0; j < 4; ++j) {
        double m = 0.9 * m1[j];
        m = m + cu[j];
        m = m - (double)s1v[j];
        spv[j] = (m > 1.0) ? 1.0f : 0.0f;
        m1[j] = m;
      }
      s1 = sp;
      *reinterpret_cast<float4*>(&spkl[sl * BN + q4]) = sp;
    }
    __syncthreads();
    if (pb) {
      const float* sr = &spkl[ss * BN];
      const float* wr = &w2l[oo * HID_DIM];
      double a0 = 0.0, a1 = 0.0, a2 = 0.0, a3 = 0.0;
#pragma unroll
      for (int h = 0; h < 100; h += 4) {
        a0 = fma((double)sr[h],     (double)wr[h],     a0);
        a1 = fma((double)sr[h + 1], (double)wr[h + 1], a1);
        a2 = fma((double)sr[h + 2], (double)wr[h + 2], a2);
        a3 = fma((double)sr[h + 3], (double)wr[h + 3], a3);
      }
      const double a = (a0 + a1) + (a2 + a3);
      double m = 0.9 * m2;
      m = m + a;
      m = m - (double)s2;
      const float sp = (m > 1.0) ? 1.0f : 0.0f;
      m2 = m; s2 = sp; oacc += sp;
    }
    __syncthreads();
  }

  if (pa) {
    double2* mp = reinterpret_cast<double2*>(mem1s + aOff);
    mp[0] = make_double2(m1[0], m1[1]);
    mp[1] = make_double2(m1[2], m1[3]);
    *reinterpret_cast<float4*>(spk1s + aOff) = s1;
  }
  if (pb) {
    mem2s[bOff] = m2; spk2s[bOff] = s2; outs[bOff] = oacc;
    if (isLast) dout[bOff] = oacc;
  }
}

// ---------------- host ----------------
extern "C" void kernel_launch(void* const* d_in, const int* in_sizes, int n_in,
                              void* d_out, int out_size, void* d_ws, size_t ws_size,
                              hipStream_t stream) {
  const float* x  = (const float*)d_in[0];   // [100,2048,784]
  const float* w1 = (const float*)d_in[1];   // [100,784]
  const float* w2 = (const float*)d_in[2];   // [10,100]
  float* out = (float*)d_out;

  char* ws = (char*)d_ws;
  // byte offsets: w1p(f) 351,232 | mem1(d) 1,835,008 | spk1(f) 917,504 |
  //               mem2(d) 163,840 | spk2(f) 81,920 | outacc(f) 81,920 | cur(d)...
  float*  w1p   = (float*) (ws);
  double* mem1s = (double*)(ws +  351232);
  float*  spk1s = (float*) (ws + 2186240);
  double* mem2s = (double*)(ws + 3103744);
  float*  spk2s = (float*) (ws + 3267584);
  float*  outs  = (float*) (ws + 3349504);
  double* cur   = (double*)(ws + 3431424);

  pad_w1<<<dim3((BN * IN_DIM + 255) / 256), dim3(256), 0, stream>>>(w1, w1p);

  const size_t perT = (size_t)B_SZ * BN * 8;   // 1,835,008 B of cur per timestep
  size_t curCap = ws_size > (size_t)3431424 ? ws_size - 3431424 : 0;
  int Tc = (int)(curCap / perT);
  if (Tc > T_STEPS) Tc = T_STEPS;
  if (Tc < 1) Tc = 1;

  for (int t0 = 0; t0 < T_STEPS; t0 += Tc) {
    const int ct = (T_STEPS - t0 < Tc) ? (T_STEPS - t0) : Tc;
    snn_gemm1<<<dim3(ct * (B_SZ / BMR)), dim3(256), 0, stream>>>(
        x + (size_t)t0 * B_SZ * IN_DIM, w1p, cur);
    snn_recur<<<dim3(B_SZ / 8), dim3(256), 0, stream>>>(
        cur, w2, mem1s, spk1s, mem2s, spk2s, outs, out,
        ct, (t0 == 0) ? 1 : 0, (t0 + ct >= T_STEPS) ? 1 : 0);
  }
}

// Round 7
// 809.931 us; speedup vs baseline: 1.8510x; 1.5140x over previous
//
#include <hip/hip_runtime.h>

#define T_STEPS 100
#define B_SZ    2048
#define IN_DIM  784
#define HID_DIM 100
#define OUT_DIM 10
#define BN      112           // padded hidden (7 x 16)
#define BMR     128           // rows per block
#define KC      16
#define NSTEP   (IN_DIM / KC) // 49
#define LDP     144           // LDS row stride (floats): 144%32==16 -> 2-way max (free)

typedef double f64x4 __attribute__((ext_vector_type(4)));
#define MFMA64(a, b, c) __builtin_amdgcn_mfma_f64_16x16x4f64((a), (b), (c), 0, 0, 0)

// ---------------- pad w1 to [112][784] float (rows 100..111 = 0) ----------------
__global__ void pad_w1(const float* __restrict__ w1, float* __restrict__ w1p) {
  int i = blockIdx.x * 256 + threadIdx.x;
  if (i < BN * IN_DIM) w1p[i] = (i < HID_DIM * IN_DIM) ? w1[i] : 0.0f;
}

// ---------------- Phase A: fp64 MFMA GEMM, self-calibrated D-map, 2 waves/SIMD ----------------
__global__ __launch_bounds__(256, 2)
void snn_gemm1(const float* __restrict__ x,     // [rows][784] (chunk-offset)
               const float* __restrict__ w1p,   // [112][784]
               double* __restrict__ cur)        // [rows][112]
{
  const int tid  = threadIdx.x;
  const int lane = tid & 63;
  const int wv   = tid >> 6;      // 0..3
  const int kg   = lane >> 4;     // 0..3 (k-slot label)
  const int il   = lane & 15;     // row/col label
  const long rowBase = (long)blockIdx.x * BMR;

  __shared__ float xls[2][KC][LDP];   // 18432 B
  __shared__ float wls[2][KC][LDP];   // 18432 B

  // staging maps: thread t -> 8 floats of one row, k-half (t&1)*8
  const int  srow = tid >> 1;                  // x: 0..127 ; w: 0..111 (tid<224)
  const int  skh  = (tid & 1) * 8;
  const float* xsrc = x   + (rowBase + srow) * (long)IN_DIM + skh;
  const float* wsrc = w1p + (long)srow * IN_DIM + skh;
  const bool   dow  = tid < 2 * BN;            // 224 threads stage w

  float4 xa, xb, wa, wb;
  auto LOAD = [&](int s) {
    const float4* xp = reinterpret_cast<const float4*>(xsrc + s * KC);
    xa = xp[0]; xb = xp[1];
    if (dow) {
      const float4* wp = reinterpret_cast<const float4*>(wsrc + s * KC);
      wa = wp[0]; wb = wp[1];
    }
  };
  auto STORE = [&](int buf) {
    xls[buf][skh + 0][srow] = xa.x; xls[buf][skh + 1][srow] = xa.y;
    xls[buf][skh + 2][srow] = xa.z; xls[buf][skh + 3][srow] = xa.w;
    xls[buf][skh + 4][srow] = xb.x; xls[buf][skh + 5][srow] = xb.y;
    xls[buf][skh + 6][srow] = xb.z; xls[buf][skh + 7][srow] = xb.w;
    if (dow) {
      wls[buf][skh + 0][srow] = wa.x; wls[buf][skh + 1][srow] = wa.y;
      wls[buf][skh + 2][srow] = wa.z; wls[buf][skh + 3][srow] = wa.w;
      wls[buf][skh + 4][srow] = wb.x; wls[buf][skh + 5][srow] = wb.y;
      wls[buf][skh + 6][srow] = wb.z; wls[buf][skh + 7][srow] = wb.w;
    }
  };

  // issue first global loads, then run calibration probes under their latency
  LOAD(0);

  // ---- self-calibration: discover the true (lane,reg)->(row,col) D map ----
  f64x4 z = {0.0, 0.0, 0.0, 0.0};
  const double eil = (double)il;
  const double d0 = (kg == 0) ? 1.0 : 0.0;
  const double d1 = (kg == 1) ? 1.0 : 0.0;
  const double d2 = (kg == 2) ? 1.0 : 0.0;
  const double d3 = (kg == 3) ? 1.0 : 0.0;
  const f64x4 Prow0 = MFMA64(eil, d0, z);
  const f64x4 Prow1 = MFMA64(eil, d1, z);
  const f64x4 Pcol0 = MFMA64(d0, eil, z);
  const f64x4 Pcol1 = MFMA64(d1, eil, z);
  const f64x4 Pv0   = MFMA64(d0, d0, z);
  const f64x4 Pv1   = MFMA64(d1, d1, z);
  const f64x4 Pv2   = MFMA64(d2, d2, z);
  const f64x4 Pv3   = MFMA64(d3, d3, z);

  bool okl = true;
  int rowof[4], colof[4];
#pragma unroll
  for (int r = 0; r < 4; ++r) {
    okl = okl && (Pv0[r] == 1.0) && (Pv1[r] == 1.0) && (Pv2[r] == 1.0) && (Pv3[r] == 1.0);
    okl = okl && (Prow0[r] == Prow1[r]) && (Pcol0[r] == Pcol1[r]);
    const int rr = (int)Prow0[r];
    const int cc = (int)Pcol0[r];
    okl = okl && ((double)rr == Prow0[r]) && (rr >= 0) && (rr < 16);
    okl = okl && ((double)cc == Pcol0[r]) && (cc >= 0) && (cc < 16);
    rowof[r] = rr; colof[r] = cc;
  }
  if (__all(okl ? 1 : 0) == 0) {       // canonical fallback (validated map expected)
#pragma unroll
    for (int r = 0; r < 4; ++r) { rowof[r] = kg * 4 + r; colof[r] = il; }
  }

  f64x4 acc[2][7];
#pragma unroll
  for (int rt = 0; rt < 2; ++rt)
#pragma unroll
    for (int ht = 0; ht < 7; ++ht) acc[rt][ht] = z;

  STORE(0); LOAD(1);
  __syncthreads();

#pragma unroll 1
  for (int s = 0; s < NSTEP; ++s) {
    if (s + 1 < NSTEP) STORE((s + 1) & 1);
    if (s + 2 < NSTEP) LOAD(s + 2);
    const int buf = s & 1;

#pragma unroll
    for (int kk = 0; kk < 4; ++kk) {
      const int kr = kk * 4 + kg;
      const double a0 = (double)xls[buf][kr][wv * 32 + il];
      const double a1 = (double)xls[buf][kr][wv * 32 + 16 + il];
      double b[7];
#pragma unroll
      for (int ht = 0; ht < 7; ++ht)
        b[ht] = (double)wls[buf][kr][ht * 16 + il];
#pragma unroll
      for (int ht = 0; ht < 7; ++ht) {
        acc[0][ht] = MFMA64(a0, b[ht], acc[0][ht]);
        acc[1][ht] = MFMA64(a1, b[ht], acc[1][ht]);
      }
    }
    __syncthreads();
  }

  // epilogue through the calibrated D map
#pragma unroll
  for (int rt = 0; rt < 2; ++rt) {
    const long r0 = rowBase + wv * 32 + rt * 16;
#pragma unroll
    for (int ht = 0; ht < 7; ++ht)
#pragma unroll
      for (int m = 0; m < 4; ++m)
        cur[(r0 + rowof[m]) * BN + ht * 16 + colof[m]] = acc[rt][ht][m];
  }
}

// ---------------- Phase B: serial-in-time recursion, fp64 state (proven numerics) ----------------
__global__ __launch_bounds__(256)
void snn_recur(const double* __restrict__ cur,  // [chunkT][2048][112]
               const float* __restrict__ w2,    // [10][100]
               double* __restrict__ mem1s, float* __restrict__ spk1s,  // [2048][112]
               double* __restrict__ mem2s, float* __restrict__ spk2s,  // [2048][10]
               float* __restrict__ outs,
               float* __restrict__ dout,
               int chunkT, int isFirst, int isLast)
{
  const int tid = threadIdx.x;
  const int b0  = blockIdx.x * 8;
  __shared__ float w2l[OUT_DIM * HID_DIM];   // 1000
  __shared__ float spkl[8 * BN];             // 896

  if (tid < 250)
    reinterpret_cast<float4*>(w2l)[tid] = reinterpret_cast<const float4*>(w2)[tid];

  const bool pa = tid < 224;                 // 8 samples * 112 / 4
  const int  sl = tid / 28, q4 = (tid % 28) * 4;
  const long aOff = (long)(b0 + sl) * BN + q4;
  double m1[4] = {0.0, 0.0, 0.0, 0.0};
  float4 s1 = make_float4(0.f, 0.f, 0.f, 0.f);
  if (pa && !isFirst) {
    const double2* mp = reinterpret_cast<const double2*>(mem1s + aOff);
    double2 a = mp[0], b = mp[1];
    m1[0] = a.x; m1[1] = a.y; m1[2] = b.x; m1[3] = b.y;
    s1 = *reinterpret_cast<const float4*>(spk1s + aOff);
  }

  const bool pb = tid < 80;
  const int  ss = tid / 10, oo = tid % 10;
  const long bOff = (long)b0 * OUT_DIM + tid;
  double m2 = 0.0;
  float s2 = 0.f, oacc = 0.f;
  if (pb && !isFirst) { m2 = mem2s[bOff]; s2 = spk2s[bOff]; oacc = outs[bOff]; }

  __syncthreads();

  for (int tt = 0; tt < chunkT; ++tt) {
    if (pa) {
      const double2* cp = reinterpret_cast<const double2*>(
          cur + ((long)tt * B_SZ + b0 + sl) * BN + q4);
      const double2 ca = cp[0], cb = cp[1];
      double cu[4] = {ca.x, ca.y, cb.x, cb.y};
      float4 sp;
      float* spv = &sp.x;
      const float* s1v = &s1.x;
#pragma unroll
      for (int j = 0; j < 4; ++j) {
        double m = 0.9 * m1[j];
        m = m + cu[j];
        m = m - (double)s1v[j];
        spv[j] = (m > 1.0) ? 1.0f : 0.0f;
        m1[j] = m;
      }
      s1 = sp;
      *reinterpret_cast<float4*>(&spkl[sl * BN + q4]) = sp;
    }
    __syncthreads();
    if (pb) {
      const float* sr = &spkl[ss * BN];
      const float* wr = &w2l[oo * HID_DIM];
      double a0 = 0.0, a1 = 0.0, a2 = 0.0, a3 = 0.0;
#pragma unroll
      for (int h = 0; h < 100; h += 4) {
        a0 = fma((double)sr[h],     (double)wr[h],     a0);
        a1 = fma((double)sr[h + 1], (double)wr[h + 1], a1);
        a2 = fma((double)sr[h + 2], (double)wr[h + 2], a2);
        a3 = fma((double)sr[h + 3], (double)wr[h + 3], a3);
      }
      const double a = (a0 + a1) + (a2 + a3);
      double m = 0.9 * m2;
      m = m + a;
      m = m - (double)s2;
      const float sp = (m > 1.0) ? 1.0f : 0.0f;
      m2 = m; s2 = sp; oacc += sp;
    }
    __syncthreads();
  }

  if (pa) {
    double2* mp = reinterpret_cast<double2*>(mem1s + aOff);
    mp[0] = make_double2(m1[0], m1[1]);
    mp[1] = make_double2(m1[2], m1[3]);
    *reinterpret_cast<float4*>(spk1s + aOff) = s1;
  }
  if (pb) {
    mem2s[bOff] = m2; spk2s[bOff] = s2; outs[bOff] = oacc;
    if (isLast) dout[bOff] = oacc;
  }
}

// ---------------- host ----------------
extern "C" void kernel_launch(void* const* d_in, const int* in_sizes, int n_in,
                              void* d_out, int out_size, void* d_ws, size_t ws_size,
                              hipStream_t stream) {
  const float* x  = (const float*)d_in[0];   // [100,2048,784]
  const float* w1 = (const float*)d_in[1];   // [100,784]
  const float* w2 = (const float*)d_in[2];   // [10,100]
  float* out = (float*)d_out;

  char* ws = (char*)d_ws;
  // byte offsets: w1p(f) 351,232 | mem1(d) 1,835,008 | spk1(f) 917,504 |
  //               mem2(d) 163,840 | spk2(f) 81,920 | outacc(f) 81,920 | cur(d)...
  float*  w1p   = (float*) (ws);
  double* mem1s = (double*)(ws +  351232);
  float*  spk1s = (float*) (ws + 2186240);
  double* mem2s = (double*)(ws + 3103744);
  float*  spk2s = (float*) (ws + 3267584);
  float*  outs  = (float*) (ws + 3349504);
  double* cur   = (double*)(ws + 3431424);

  pad_w1<<<dim3((BN * IN_DIM + 255) / 256), dim3(256), 0, stream>>>(w1, w1p);

  const size_t perT = (size_t)B_SZ * BN * 8;   // 1,835,008 B of cur per timestep
  size_t curCap = ws_size > (size_t)3431424 ? ws_size - 3431424 : 0;
  int Tc = (int)(curCap / perT);
  if (Tc > T_STEPS) Tc = T_STEPS;
  if (Tc < 1) Tc = 1;

  for (int t0 = 0; t0 < T_STEPS; t0 += Tc) {
    const int ct = (T_STEPS - t0 < Tc) ? (T_STEPS - t0) : Tc;
    snn_gemm1<<<dim3(ct * (B_SZ / BMR)), dim3(256), 0, stream>>>(
        x + (size_t)t0 * B_SZ * IN_DIM, w1p, cur);
    snn_recur<<<dim3(B_SZ / 8), dim3(256), 0, stream>>>(
        cur, w2, mem1s, spk1s, mem2s, spk2s, outs, out,
        ct, (t0 == 0) ? 1 : 0, (t0 + ct >= T_STEPS) ? 1 : 0);
  }
}

// Round 8
// 720.724 us; speedup vs baseline: 2.0801x; 1.1238x over previous
//
#include <hip/hip_runtime.h>

#define T_STEPS 100
#define B_SZ    2048
#define IN_DIM  784
#define HID_DIM 100
#define OUT_DIM 10
#define BN      112           // padded hidden (7 x 16)
#define BMR     64            // rows per block (wave = 16 rows x 112 cols)
#define KC      16
#define NSTEP   (IN_DIM / KC) // 49
#define XLP     80            // x LDS k-stride: 80%32==16 -> 2-way (free) frag reads
#define WLP     112           // w LDS k-stride: 112%32==16 -> free frag reads

typedef double f64x4 __attribute__((ext_vector_type(4)));
#define MFMA64(a, b, c) __builtin_amdgcn_mfma_f64_16x16x4f64((a), (b), (c), 0, 0, 0)

// ---------------- pad w1 to [112][784] float (rows 100..111 = 0) ----------------
__global__ void pad_w1(const float* __restrict__ w1, float* __restrict__ w1p) {
  int i = blockIdx.x * 256 + threadIdx.x;
  if (i < BN * IN_DIM) w1p[i] = (i < HID_DIM * IN_DIM) ? w1[i] : 0.0f;
}

// ---------------- Phase A: fp64 MFMA GEMM, self-calibrated D-map, 3 waves/SIMD ----------------
__global__ __launch_bounds__(256, 3)
void snn_gemm1(const float* __restrict__ x,     // [rows][784] (chunk-offset)
               const float* __restrict__ w1p,   // [112][784]
               double* __restrict__ cur)        // [rows][112]
{
  const int tid  = threadIdx.x;
  const int lane = tid & 63;
  const int wv   = tid >> 6;      // 0..3
  const int kg   = lane >> 4;     // 0..3 (k-slot label)
  const int il   = lane & 15;     // row/col label
  const long rowBase = (long)blockIdx.x * BMR;

  __shared__ float xls[2][KC][XLP];   // 10240 B
  __shared__ float wls[2][KC][WLP];   // 14336 B

  // staging maps
  // x: 64 rows x 16 k = 256 float4; thread t: row=t>>2, kq=(t&3)*4
  const int xrow = tid >> 2;
  const int xq   = (tid & 3) * 4;
  const float* xsrc = x + (rowBase + xrow) * (long)IN_DIM + xq;
  // w: 112 rows x 16 k = 448 float4; thread t<224: row=t>>1, skh=(t&1)*8
  const int  wrow = tid >> 1;
  const int  skh  = (tid & 1) * 8;
  const float* wsrc = w1p + (long)wrow * IN_DIM + skh;
  const bool   dow  = tid < 2 * BN;   // 224 threads stage w

  float4 xg, wa, wb;
  auto LOAD = [&](int s) {
    xg = *reinterpret_cast<const float4*>(xsrc + s * KC);
    if (dow) {
      const float4* wp = reinterpret_cast<const float4*>(wsrc + s * KC);
      wa = wp[0]; wb = wp[1];
    }
  };
  auto STORE = [&](int buf) {
    xls[buf][xq + 0][xrow] = xg.x; xls[buf][xq + 1][xrow] = xg.y;
    xls[buf][xq + 2][xrow] = xg.z; xls[buf][xq + 3][xrow] = xg.w;
    if (dow) {
      wls[buf][skh + 0][wrow] = wa.x; wls[buf][skh + 1][wrow] = wa.y;
      wls[buf][skh + 2][wrow] = wa.z; wls[buf][skh + 3][wrow] = wa.w;
      wls[buf][skh + 4][wrow] = wb.x; wls[buf][skh + 5][wrow] = wb.y;
      wls[buf][skh + 6][wrow] = wb.z; wls[buf][skh + 7][wrow] = wb.w;
    }
  };

  // issue first global loads, run calibration probes under their latency
  LOAD(0);

  // ---- self-calibration: discover the true (lane,reg)->(row,col) D map ----
  f64x4 z = {0.0, 0.0, 0.0, 0.0};
  const double eil = (double)il;
  const double d0 = (kg == 0) ? 1.0 : 0.0;
  const double d1 = (kg == 1) ? 1.0 : 0.0;
  const double d2 = (kg == 2) ? 1.0 : 0.0;
  const double d3 = (kg == 3) ? 1.0 : 0.0;
  const f64x4 Prow0 = MFMA64(eil, d0, z);
  const f64x4 Prow1 = MFMA64(eil, d1, z);
  const f64x4 Pcol0 = MFMA64(d0, eil, z);
  const f64x4 Pcol1 = MFMA64(d1, eil, z);
  const f64x4 Pv0   = MFMA64(d0, d0, z);
  const f64x4 Pv1   = MFMA64(d1, d1, z);
  const f64x4 Pv2   = MFMA64(d2, d2, z);
  const f64x4 Pv3   = MFMA64(d3, d3, z);

  bool okl = true;
  int rowof[4], colof[4];
#pragma unroll
  for (int r = 0; r < 4; ++r) {
    okl = okl && (Pv0[r] == 1.0) && (Pv1[r] == 1.0) && (Pv2[r] == 1.0) && (Pv3[r] == 1.0);
    okl = okl && (Prow0[r] == Prow1[r]) && (Pcol0[r] == Pcol1[r]);
    const int rr = (int)Prow0[r];
    const int cc = (int)Pcol0[r];
    okl = okl && ((double)rr == Prow0[r]) && (rr >= 0) && (rr < 16);
    okl = okl && ((double)cc == Pcol0[r]) && (cc >= 0) && (cc < 16);
    rowof[r] = rr; colof[r] = cc;
  }
  if (__all(okl ? 1 : 0) == 0) {       // canonical fallback (not expected)
#pragma unroll
    for (int r = 0; r < 4; ++r) { rowof[r] = kg * 4 + r; colof[r] = il; }
  }

  f64x4 acc[7];
#pragma unroll
  for (int ht = 0; ht < 7; ++ht) acc[ht] = z;

  STORE(0); LOAD(1);
  __syncthreads();

#pragma unroll 1
  for (int s = 0; s < NSTEP; ++s) {
    if (s + 1 < NSTEP) STORE((s + 1) & 1);
    if (s + 2 < NSTEP) LOAD(s + 2);
    const int buf = s & 1;

#pragma unroll
    for (int kk = 0; kk < 4; ++kk) {
      const int kr = kk * 4 + kg;
      const double a0 = (double)xls[buf][kr][wv * 16 + il];
      double b[7];
#pragma unroll
      for (int ht = 0; ht < 7; ++ht)
        b[ht] = (double)wls[buf][kr][ht * 16 + il];
#pragma unroll
      for (int ht = 0; ht < 7; ++ht)
        acc[ht] = MFMA64(a0, b[ht], acc[ht]);
    }
    __syncthreads();
  }

  // epilogue through the calibrated D map
  const long r0 = rowBase + wv * 16;
#pragma unroll
  for (int ht = 0; ht < 7; ++ht)
#pragma unroll
    for (int m = 0; m < 4; ++m)
      cur[(r0 + rowof[m]) * BN + ht * 16 + colof[m]] = acc[ht][m];
}

// ---------------- Phase B: serial-in-time recursion, fp64 state ----------------
// 512 blocks x 4 samples; cur prefetched one step ahead; layer-2 dot split over 2 threads.
__global__ __launch_bounds__(256)
void snn_recur(const double* __restrict__ cur,  // [chunkT][2048][112]
               const float* __restrict__ w2,    // [10][100]
               double* __restrict__ mem1s, float* __restrict__ spk1s,  // [2048][112]
               double* __restrict__ mem2s, float* __restrict__ spk2s,  // [2048][10]
               float* __restrict__ outs,
               float* __restrict__ dout,
               int chunkT, int isFirst, int isLast)
{
  const int tid = threadIdx.x;
  const int b0  = blockIdx.x * 4;              // 4 samples per block
  __shared__ float w2l[OUT_DIM * HID_DIM];     // 1000
  __shared__ float spkl[4 * BN];               // 448

  if (tid < 250)
    reinterpret_cast<float4*>(w2l)[tid] = reinterpret_cast<const float4*>(w2)[tid];

  const bool pa = tid < 112;                   // 4 samples * 112 / 4
  const int  sl = tid / 28, q4 = (tid % 28) * 4;
  const long aOff = (long)(b0 + sl) * BN + q4;
  double m1[4] = {0.0, 0.0, 0.0, 0.0};
  float4 s1 = make_float4(0.f, 0.f, 0.f, 0.f);
  if (pa && !isFirst) {
    const double2* mp = reinterpret_cast<const double2*>(mem1s + aOff);
    double2 a = mp[0], b = mp[1];
    m1[0] = a.x; m1[1] = a.y; m1[2] = b.x; m1[3] = b.y;
    s1 = *reinterpret_cast<const float4*>(spk1s + aOff);
  }

  const bool pb = tid < 80;                    // pair p=tid>>1 -> (sample, out); half=tid&1
  const int  pp = tid >> 1, hf = tid & 1;
  const int  ss = pp / 10, oo = pp % 10;
  const long bOff = (long)b0 * OUT_DIM + pp;
  double m2 = 0.0;
  float s2 = 0.f, oacc = 0.f;
  if (pb && !isFirst && hf == 0) { m2 = mem2s[bOff]; s2 = spk2s[bOff]; oacc = outs[bOff]; }

  __syncthreads();

  // prefetch pipeline on cur
  double2 ca, cb;
  if (pa) {
    const double2* cp = reinterpret_cast<const double2*>(cur + (long)b0 * BN + sl * BN + q4);
    ca = cp[0]; cb = cp[1];
  }

  for (int tt = 0; tt < chunkT; ++tt) {
    if (pa) {
      double cu[4] = {ca.x, ca.y, cb.x, cb.y};
      // issue next-step load now; completes under the dot phase
      const int tn = (tt + 1 < chunkT) ? tt + 1 : tt;
      const double2* cp = reinterpret_cast<const double2*>(
          cur + ((long)tn * B_SZ + b0 + sl) * BN + q4);
      ca = cp[0]; cb = cp[1];

      float4 sp;
      float* spv = &sp.x;
      const float* s1v = &s1.x;
#pragma unroll
      for (int j = 0; j < 4; ++j) {
        double m = 0.9 * m1[j];
        m = m + cu[j];
        m = m - (double)s1v[j];
        spv[j] = (m > 1.0) ? 1.0f : 0.0f;
        m1[j] = m;
      }
      s1 = sp;
      *reinterpret_cast<float4*>(&spkl[sl * BN + q4]) = sp;
    }
    __syncthreads();
    if (pb) {
      const float* sr = &spkl[ss * BN] + hf * 50;
      const float* wr = &w2l[oo * HID_DIM] + hf * 50;
      double a0 = 0.0, a1 = 0.0;
#pragma unroll
      for (int h = 0; h < 50; h += 2) {        // 50 per half; order-free in fp64
        a0 = fma((double)sr[h],     (double)wr[h],     a0);
        a1 = fma((double)sr[h + 1], (double)wr[h + 1], a1);
      }
      double a = a0 + a1;
      a = a + __shfl_xor(a, 1);                // combine halves
      if (hf == 0) {
        double m = 0.9 * m2;
        m = m + a;
        m = m - (double)s2;
        const float sp = (m > 1.0) ? 1.0f : 0.0f;
        m2 = m; s2 = sp; oacc += sp;
      }
    }
    __syncthreads();
  }

  if (pa) {
    double2* mp = reinterpret_cast<double2*>(mem1s + aOff);
    mp[0] = make_double2(m1[0], m1[1]);
    mp[1] = make_double2(m1[2], m1[3]);
    *reinterpret_cast<float4*>(spk1s + aOff) = s1;
  }
  if (pb && hf == 0) {
    mem2s[bOff] = m2; spk2s[bOff] = s2; outs[bOff] = oacc;
    if (isLast) dout[bOff] = oacc;
  }
}

// ---------------- host ----------------
extern "C" void kernel_launch(void* const* d_in, const int* in_sizes, int n_in,
                              void* d_out, int out_size, void* d_ws, size_t ws_size,
                              hipStream_t stream) {
  const float* x  = (const float*)d_in[0];   // [100,2048,784]
  const float* w1 = (const float*)d_in[1];   // [100,784]
  const float* w2 = (const float*)d_in[2];   // [10,100]
  float* out = (float*)d_out;

  char* ws = (char*)d_ws;
  // byte offsets: w1p(f) 351,232 | mem1(d) 1,835,008 | spk1(f) 917,504 |
  //               mem2(d) 163,840 | spk2(f) 81,920 | outacc(f) 81,920 | cur(d)...
  float*  w1p   = (float*) (ws);
  double* mem1s = (double*)(ws +  351232);
  float*  spk1s = (float*) (ws + 2186240);
  double* mem2s = (double*)(ws + 3103744);
  float*  spk2s = (float*) (ws + 3267584);
  float*  outs  = (float*) (ws + 3349504);
  double* cur   = (double*)(ws + 3431424);

  pad_w1<<<dim3((BN * IN_DIM + 255) / 256), dim3(256), 0, stream>>>(w1, w1p);

  const size_t perT = (size_t)B_SZ * BN * 8;   // 1,835,008 B of cur per timestep
  size_t curCap = ws_size > (size_t)3431424 ? ws_size - 3431424 : 0;
  int Tc = (int)(curCap / perT);
  if (Tc > T_STEPS) Tc = T_STEPS;
  if (Tc < 1) Tc = 1;

  for (int t0 = 0; t0 < T_STEPS; t0 += Tc) {
    const int ct = (T_STEPS - t0 < Tc) ? (T_STEPS - t0) : Tc;
    snn_gemm1<<<dim3(ct * (B_SZ / BMR)), dim3(256), 0, stream>>>(
        x + (size_t)t0 * B_SZ * IN_DIM, w1p, cur);
    snn_recur<<<dim3(B_SZ / 4), dim3(256), 0, stream>>>(
        cur, w2, mem1s, spk1s, mem2s, spk2s, outs, out,
        ct, (t0 == 0) ? 1 : 0, (t0 + ct >= T_STEPS) ? 1 : 0);
  }
}